// Round 1
// baseline (5315.367 us; speedup 1.0000x reference)
//
#include <hip/hip_runtime.h>
#include <math.h>

#define L_SEQ 577
#define BATCH 8
#define CDIM  768
#define NHEAD 12
#define ROWS  (L_SEQ * BATCH)      // 4616
#define LBC   ((size_t)ROWS * CDIM) // 3545088

__device__ __forceinline__ float wave_sum(float v) {
#pragma unroll
  for (int o = 32; o > 0; o >>= 1) v += __shfl_xor(v, o);
  return v;
}
__device__ __forceinline__ float wave_max(float v) {
#pragma unroll
  for (int o = 32; o > 0; o >>= 1) v = fmaxf(v, __shfl_xor(v, o));
  return v;
}

// -------- LayerNorm: one wave per row of 768 --------
__global__ __launch_bounds__(256) void ln_kernel(
    const float* __restrict__ x, const float* __restrict__ g,
    const float* __restrict__ bta, float* __restrict__ out, int rows)
{
  const int wave = threadIdx.x >> 6, lane = threadIdx.x & 63;
  const int r = blockIdx.x * 4 + wave;
  if (r >= rows) return;
  const float* xr = x + (size_t)r * CDIM;
  float v[12];
  float s = 0.f, s2 = 0.f;
#pragma unroll
  for (int i = 0; i < 12; ++i) {
    v[i] = xr[lane + 64 * i];
    s += v[i];
    s2 += v[i] * v[i];
  }
  s = wave_sum(s); s2 = wave_sum(s2);
  const float mu = s * (1.f / 768.f);
  const float var = s2 * (1.f / 768.f) - mu * mu;
  const float rs = rsqrtf(var + 1e-5f);
  float* orow = out + (size_t)r * CDIM;
#pragma unroll
  for (int i = 0; i < 12; ++i) {
    const int c = lane + 64 * i;
    orow[c] = (v[i] - mu) * rs * g[c] + bta[c];
  }
}

// -------- fp32 GEMM: C[M,N] = A[M,K] @ W[N,K]^T + bias (+epilogue) --------
enum { EPI_NONE = 0, EPI_ADD = 1, EPI_GELU = 2 };

template <int EPI>
__global__ __launch_bounds__(256) void gemm_kernel(
    const float* __restrict__ A, int lda,
    const float* __restrict__ W, int K,
    const float* __restrict__ bias,
    float* __restrict__ C, int ldc,
    const float* __restrict__ res, int ldr,
    int M)
{
  __shared__ float As[16][128];
  __shared__ float Bs[16][128];
  const int t = threadIdx.x;
  const int tx = t & 15, ty = t >> 4;
  const int m0 = blockIdx.x * 128, n0 = blockIdx.y * 128;
  const int lrow = t >> 1;            // 0..127
  const int lkq = (t & 1) << 2;       // 0 or 4
  const int am = m0 + lrow;
  const bool avalid = am < M;
  const float* aptr = A + (size_t)(avalid ? am : 0) * lda + lkq;
  const float* bptr = W + (size_t)(n0 + lrow) * K + lkq;
  float acc[8][8] = {};

  for (int k0 = 0; k0 < K; k0 += 16) {
    float4 av0 = avalid ? *(const float4*)(aptr + k0)     : make_float4(0.f, 0.f, 0.f, 0.f);
    float4 av1 = avalid ? *(const float4*)(aptr + k0 + 8) : make_float4(0.f, 0.f, 0.f, 0.f);
    float4 bv0 = *(const float4*)(bptr + k0);
    float4 bv1 = *(const float4*)(bptr + k0 + 8);
    __syncthreads();
    As[lkq + 0][lrow] = av0.x; As[lkq + 1][lrow] = av0.y;
    As[lkq + 2][lrow] = av0.z; As[lkq + 3][lrow] = av0.w;
    As[lkq + 8][lrow] = av1.x; As[lkq + 9][lrow] = av1.y;
    As[lkq +10][lrow] = av1.z; As[lkq +11][lrow] = av1.w;
    Bs[lkq + 0][lrow] = bv0.x; Bs[lkq + 1][lrow] = bv0.y;
    Bs[lkq + 2][lrow] = bv0.z; Bs[lkq + 3][lrow] = bv0.w;
    Bs[lkq + 8][lrow] = bv1.x; Bs[lkq + 9][lrow] = bv1.y;
    Bs[lkq +10][lrow] = bv1.z; Bs[lkq +11][lrow] = bv1.w;
    __syncthreads();
#pragma unroll
    for (int kk = 0; kk < 16; ++kk) {
      float a[8], bb[8];
      *(float4*)&a[0] = *(const float4*)&As[kk][ty * 8];
      *(float4*)&a[4] = *(const float4*)&As[kk][ty * 8 + 4];
      *(float4*)&bb[0] = *(const float4*)&Bs[kk][tx * 8];
      *(float4*)&bb[4] = *(const float4*)&Bs[kk][tx * 8 + 4];
#pragma unroll
      for (int i = 0; i < 8; ++i)
#pragma unroll
        for (int j = 0; j < 8; ++j)
          acc[i][j] = fmaf(a[i], bb[j], acc[i][j]);
    }
  }

  float bb[8];
#pragma unroll
  for (int j = 0; j < 8; ++j) bb[j] = bias[n0 + tx * 8 + j];
#pragma unroll
  for (int i = 0; i < 8; ++i) {
    const int m = m0 + ty * 8 + i;
    if (m >= M) continue;
    float* crow = C + (size_t)m * ldc + n0 + tx * 8;
    const float* rrow = (EPI == EPI_ADD) ? (res + (size_t)m * ldr + n0 + tx * 8) : nullptr;
#pragma unroll
    for (int j = 0; j < 8; ++j) {
      float val = acc[i][j] + bb[j];
      if (EPI == EPI_GELU) val = val / (1.f + __expf(-1.702f * val));
      if (EPI == EPI_ADD) val += rrow[j];
      crow[j] = val;
    }
  }
}

// -------- v2v attention: one wave per (b,h,row); two softmaxes (q·k and v·v) --------
__global__ __launch_bounds__(256) void attn_kernel(
    const float* __restrict__ qkv,   // [ROWS, 2304], row r = l*BATCH + b
    float* __restrict__ xo,          // [ROWS, 768]  (attn = softmax(v v^T)) @ v
    float* __restrict__ xori)        // [ROWS, 768]  (attn_ori = softmax(q k^T)) @ v
{
  __shared__ float sc[4][640];
  __shared__ float xsh[4][64];
  const int wave = threadIdx.x >> 6, lane = threadIdx.x & 63;
  const int bh = blockIdx.y;
  const int b = bh / NHEAD, h = bh - b * NHEAD;
  const int l = blockIdx.x * 4 + wave;
  const bool valid = l < L_SEQ;
  const int lc = valid ? l : (L_SEQ - 1);
  const size_t r = (size_t)lc * BATCH + b;
  const int hoff = h * 64;

  for (int att = 0; att < 2; ++att) {
    const int xoff = (att == 0) ? 0 : 1536;    // query = q or v
    const int yoff = (att == 0) ? 768 : 1536;  // key   = k or v
    __syncthreads();  // protect LDS reuse across iterations
    xsh[wave][lane] = qkv[r * 2304 + xoff + hoff + lane];
    __syncthreads();

    float sreg[10];
    float mloc = -1e30f;
#pragma unroll
    for (int c = 0; c < 10; ++c) {
      const int j = c * 64 + lane;
      const bool jv = j < L_SEQ;
      const float* yrow = qkv + (size_t)(jv ? j : 0) * BATCH * 2304 + (size_t)b * 2304 + yoff + hoff;
      float s = 0.f;
#pragma unroll
      for (int d4 = 0; d4 < 16; ++d4) {
        float4 yv = *(const float4*)(yrow + d4 * 4);
        float4 xv = *(const float4*)(&xsh[wave][d4 * 4]);
        s += xv.x * yv.x + xv.y * yv.y + xv.z * yv.z + xv.w * yv.w;
      }
      s *= 0.125f;  // 64^-0.5
      if (!jv) s = -1e30f;
      sreg[c] = s;
      mloc = fmaxf(mloc, s);
    }
    const float m = wave_max(mloc);
    float ssum = 0.f;
#pragma unroll
    for (int c = 0; c < 10; ++c) {
      const float e = __expf(sreg[c] - m);
      sc[wave][c * 64 + lane] = e;
      ssum += e;
    }
    const float rinv = 1.f / wave_sum(ssum);
    __syncthreads();  // make sc visible across lanes

    float o = 0.f;
#pragma unroll 4
    for (int j = 0; j < L_SEQ; ++j) {
      o += sc[wave][j] * qkv[(size_t)(j * BATCH + b) * 2304 + 1536 + hoff + lane];
    }
    if (valid) {
      float* dst = (att == 0) ? xori : xo;
      dst[r * CDIM + hoff + lane] = o * rinv;
    }
  }
}

extern "C" void kernel_launch(void* const* d_in, const int* in_sizes, int n_in,
                              void* d_out, int out_size, void* d_ws, size_t ws_size,
                              hipStream_t stream)
{
  const float* x_res  = (const float*)d_in[0];
  const float* x      = (const float*)d_in[1];
  const float* ln1_g  = (const float*)d_in[2];
  const float* ln1_b  = (const float*)d_in[3];
  const float* ln2_g  = (const float*)d_in[4];
  const float* ln2_b  = (const float*)d_in[5];
  const float* qkv_w  = (const float*)d_in[6];
  const float* qkv_b  = (const float*)d_in[7];
  const float* proj_w = (const float*)d_in[8];
  const float* proj_b = (const float*)d_in[9];
  const float* fc_w   = (const float*)d_in[10];
  const float* fc_b   = (const float*)d_in[11];
  const float* cproj_w= (const float*)d_in[12];
  const float* cproj_b= (const float*)d_in[13];

  float* out_x  = (float*)d_out;          // x
  float* out_q  = out_x + LBC;            // q
  float* out_k  = out_x + 2 * LBC;        // k
  float* out_v  = out_x + 3 * LBC;        // v
  float* out_xr = out_x + 4 * LBC;        // x_res

  // ws layout: [shared qkv/h region][ln][xo][xori]  (~95 MB total)
  float* wsS    = (float*)d_ws;                       // max(ROWS*2304, ROWS*3072)
  float* wsLN   = wsS + (size_t)ROWS * 3072;
  float* wsXO   = wsLN + LBC;
  float* wsXORI = wsXO + LBC;

  const dim3 blk(256);
  const dim3 gLN((ROWS + 3) / 4);
  const dim3 gQKV(37, 18);   // ceil(4616/128) x 2304/128
  const dim3 gPROJ(37, 6);   // N=768
  const dim3 gFC(37, 24);    // N=3072
  const dim3 gATT((L_SEQ + 3) / 4, BATCH * NHEAD);

  // 1. ln1(x) -> wsLN
  ln_kernel<<<gLN, blk, 0, stream>>>(x, ln1_g, ln1_b, wsLN, ROWS);
  // 2. qkv = ln1(x) @ qkv_w^T + qkv_b -> wsS  [ROWS, 2304]
  gemm_kernel<EPI_NONE><<<gQKV, blk, 0, stream>>>(wsLN, CDIM, qkv_w, CDIM, qkv_b,
                                                  wsS, 2304, nullptr, 0, ROWS);
  // 3-5. y-path projections (q, k, v1 = v_proj + x)
  gemm_kernel<EPI_NONE><<<gPROJ, blk, 0, stream>>>(wsS + 0,    2304, proj_w, CDIM, proj_b,
                                                   out_q, CDIM, nullptr, 0, ROWS);
  gemm_kernel<EPI_NONE><<<gPROJ, blk, 0, stream>>>(wsS + 768,  2304, proj_w, CDIM, proj_b,
                                                   out_k, CDIM, nullptr, 0, ROWS);
  gemm_kernel<EPI_ADD><<<gPROJ, blk, 0, stream>>>(wsS + 1536, 2304, proj_w, CDIM, proj_b,
                                                  out_v, CDIM, x, CDIM, ROWS);
  // 6. v2v attention: qkv -> xo, xori
  attn_kernel<<<gATT, blk, 0, stream>>>(wsS, wsXO, wsXORI);
  // 7. x_res_out = x_res + proj(xo)
  gemm_kernel<EPI_ADD><<<gPROJ, blk, 0, stream>>>(wsXO, CDIM, proj_w, CDIM, proj_b,
                                                  out_xr, CDIM, x_res, CDIM, ROWS);
  // 8. x1 = x + proj(xori)   (staged in out_x)
  gemm_kernel<EPI_ADD><<<gPROJ, blk, 0, stream>>>(wsXORI, CDIM, proj_w, CDIM, proj_b,
                                                  out_x, CDIM, x, CDIM, ROWS);
  // 9. MLP on v1 (in out_v): v = v1 + cproj(gelu(fc(ln2(v1))))
  ln_kernel<<<gLN, blk, 0, stream>>>(out_v, ln2_g, ln2_b, wsLN, ROWS);
  gemm_kernel<EPI_GELU><<<gFC, blk, 0, stream>>>(wsLN, CDIM, fc_w, CDIM, fc_b,
                                                 wsS, 3072, nullptr, 0, ROWS);
  gemm_kernel<EPI_ADD><<<gPROJ, blk, 0, stream>>>(wsS, 3072, cproj_w, 3072, cproj_b,
                                                  out_v, CDIM, out_v, CDIM, ROWS);
  // 10. MLP on x1 (in out_x): x = x1 + cproj(gelu(fc(ln2(x1))))
  ln_kernel<<<gLN, blk, 0, stream>>>(out_x, ln2_g, ln2_b, wsLN, ROWS);
  gemm_kernel<EPI_GELU><<<gFC, blk, 0, stream>>>(wsLN, CDIM, fc_w, CDIM, fc_b,
                                                 wsS, 3072, nullptr, 0, ROWS);
  gemm_kernel<EPI_ADD><<<gPROJ, blk, 0, stream>>>(wsS, 3072, cproj_w, 3072, cproj_b,
                                                  out_x, CDIM, out_x, CDIM, ROWS);
}

// Round 2
// 2875.224 us; speedup vs baseline: 1.8487x; 1.8487x over previous
//
#include <hip/hip_runtime.h>
#include <math.h>

#define L_SEQ 577
#define BATCH 8
#define CDIM  768
#define NHEAD 12
#define ROWS  (L_SEQ * BATCH)      // 4616
#define LBC   ((size_t)ROWS * CDIM) // 3545088

__device__ __forceinline__ float wave_sum(float v) {
#pragma unroll
  for (int o = 32; o > 0; o >>= 1) v += __shfl_xor(v, o);
  return v;
}

// -------- LayerNorm: one wave per row of 768 --------
__global__ __launch_bounds__(256) void ln_kernel(
    const float* __restrict__ x, const float* __restrict__ g,
    const float* __restrict__ bta, float* __restrict__ out, int rows)
{
  const int wave = threadIdx.x >> 6, lane = threadIdx.x & 63;
  const int r = blockIdx.x * 4 + wave;
  if (r >= rows) return;
  const float* xr = x + (size_t)r * CDIM;
  float v[12];
  float s = 0.f, s2 = 0.f;
#pragma unroll
  for (int i = 0; i < 12; ++i) {
    v[i] = xr[lane + 64 * i];
    s += v[i];
    s2 += v[i] * v[i];
  }
  s = wave_sum(s); s2 = wave_sum(s2);
  const float mu = s * (1.f / 768.f);
  const float var = s2 * (1.f / 768.f) - mu * mu;
  const float rs = rsqrtf(var + 1e-5f);
  float* orow = out + (size_t)r * CDIM;
#pragma unroll
  for (int i = 0; i < 12; ++i) {
    const int c = lane + 64 * i;
    orow[c] = (v[i] - mu) * rs * g[c] + bta[c];
  }
}

// -------- fp32 GEMM: C[M,N] = A[M,K] @ W[N,K]^T + bias (+epilogue) --------
enum { EPI_NONE = 0, EPI_ADD = 1, EPI_GELU = 2 };

template <int EPI>
__global__ __launch_bounds__(256) void gemm_kernel(
    const float* __restrict__ A, int lda,
    const float* __restrict__ W, int K,
    const float* __restrict__ bias,
    float* __restrict__ C, int ldc,
    const float* __restrict__ res, int ldr,
    int M)
{
  __shared__ float As[16][128];
  __shared__ float Bs[16][128];
  const int t = threadIdx.x;
  const int tx = t & 15, ty = t >> 4;
  const int m0 = blockIdx.x * 128, n0 = blockIdx.y * 128;
  const int lrow = t >> 1;            // 0..127
  const int lkq = (t & 1) << 2;       // 0 or 4
  const int am = m0 + lrow;
  const bool avalid = am < M;
  const float* aptr = A + (size_t)(avalid ? am : 0) * lda + lkq;
  const float* bptr = W + (size_t)(n0 + lrow) * K + lkq;
  float acc[8][8] = {};

  for (int k0 = 0; k0 < K; k0 += 16) {
    float4 av0 = avalid ? *(const float4*)(aptr + k0)     : make_float4(0.f, 0.f, 0.f, 0.f);
    float4 av1 = avalid ? *(const float4*)(aptr + k0 + 8) : make_float4(0.f, 0.f, 0.f, 0.f);
    float4 bv0 = *(const float4*)(bptr + k0);
    float4 bv1 = *(const float4*)(bptr + k0 + 8);
    __syncthreads();
    As[lkq + 0][lrow] = av0.x; As[lkq + 1][lrow] = av0.y;
    As[lkq + 2][lrow] = av0.z; As[lkq + 3][lrow] = av0.w;
    As[lkq + 8][lrow] = av1.x; As[lkq + 9][lrow] = av1.y;
    As[lkq +10][lrow] = av1.z; As[lkq +11][lrow] = av1.w;
    Bs[lkq + 0][lrow] = bv0.x; Bs[lkq + 1][lrow] = bv0.y;
    Bs[lkq + 2][lrow] = bv0.z; Bs[lkq + 3][lrow] = bv0.w;
    Bs[lkq + 8][lrow] = bv1.x; Bs[lkq + 9][lrow] = bv1.y;
    Bs[lkq +10][lrow] = bv1.z; Bs[lkq +11][lrow] = bv1.w;
    __syncthreads();
#pragma unroll
    for (int kk = 0; kk < 16; ++kk) {
      float a[8], bb[8];
      *(float4*)&a[0] = *(const float4*)&As[kk][ty * 8];
      *(float4*)&a[4] = *(const float4*)&As[kk][ty * 8 + 4];
      *(float4*)&bb[0] = *(const float4*)&Bs[kk][tx * 8];
      *(float4*)&bb[4] = *(const float4*)&Bs[kk][tx * 8 + 4];
#pragma unroll
      for (int i = 0; i < 8; ++i)
#pragma unroll
        for (int j = 0; j < 8; ++j)
          acc[i][j] = fmaf(a[i], bb[j], acc[i][j]);
    }
  }

  float bb[8];
#pragma unroll
  for (int j = 0; j < 8; ++j) bb[j] = bias[n0 + tx * 8 + j];
#pragma unroll
  for (int i = 0; i < 8; ++i) {
    const int m = m0 + ty * 8 + i;
    if (m >= M) continue;
    float* crow = C + (size_t)m * ldc + n0 + tx * 8;
    const float* rrow = (EPI == EPI_ADD) ? (res + (size_t)m * ldr + n0 + tx * 8) : nullptr;
#pragma unroll
    for (int j = 0; j < 8; ++j) {
      float val = acc[i][j] + bb[j];
      if (EPI == EPI_GELU) val = val / (1.f + __expf(-1.702f * val));
      if (EPI == EPI_ADD) val += rrow[j];
      crow[j] = val;
    }
  }
}

// -------- v2v attention, flash-style LDS-tiled --------
// Block: 256 threads = one (b,h) x 64 query rows. Grid: (10, 96).
// att=0: scores = q·k^T (out -> xori); att=1: scores = v·v^T (out -> xo).
// Both use V for the P·V product. Online softmax across 10 j-tiles of 64.
__global__ __launch_bounds__(256) void attn_kernel(
    const float* __restrict__ qkv,   // [ROWS, 2304], row r = l*BATCH + b
    float* __restrict__ xo,
    float* __restrict__ xori)
{
  __shared__ float Qs[64][65];
  __shared__ float Ks[64][65];   // holds K for scores, then V for the PV product
  __shared__ float Ps[64][65];
  const int t = threadIdx.x;
  const int tx = t & 15, ty = t >> 4;      // 16x16 thread grid, 4x4 regs each
  const int bh = blockIdx.y;
  const int b = bh / NHEAD, h = bh - b * NHEAD;
  const int q0 = blockIdx.x * 64;
  const int hoff = h * 64;
  const int lr = t >> 2;                   // 0..63: tile row this thread loads
  const int lc4 = (t & 3) * 4;             // col quad base

  for (int att = 0; att < 2; ++att) {
    const int xoff = att ? 1536 : 0;       // query = q or v
    const int yoff = att ? 1536 : 768;     // key   = k or v
    __syncthreads();                        // previous pass done with Qs
    {
      const int ql = q0 + lr;
      const int qr = ql < L_SEQ ? ql : (L_SEQ - 1);
      const float* src = qkv + (size_t)(qr * BATCH + b) * 2304 + xoff + hoff;
#pragma unroll
      for (int q = 0; q < 4; ++q)
        *(float4*)&Qs[lr][lc4 + q * 16] = *(const float4*)(src + lc4 + q * 16);
    }

    float m[4], lsum[4], O[4][4];
#pragma unroll
    for (int i = 0; i < 4; ++i) {
      m[i] = -1e30f; lsum[i] = 0.f;
#pragma unroll
      for (int d = 0; d < 4; ++d) O[i][d] = 0.f;
    }

    for (int j0 = 0; j0 < L_SEQ; j0 += 64) {
      __syncthreads();                      // prior AV done with Ks/Ps; Qs visible
      {
        const int jl = j0 + lr;
        const int jr = jl < L_SEQ ? jl : (L_SEQ - 1);
        const float* src = qkv + (size_t)(jr * BATCH + b) * 2304 + yoff + hoff;
#pragma unroll
        for (int q = 0; q < 4; ++q)
          *(float4*)&Ks[lr][lc4 + q * 16] = *(const float4*)(src + lc4 + q * 16);
      }
      __syncthreads();

      // ---- scores S[4][4] = Q[qi] . K[j], qi = ty*4+i, j = tx*4+jj ----
      float S[4][4] = {};
      for (int k = 0; k < 64; k += 4) {
        float4 qv[4], kv[4];
#pragma unroll
        for (int i = 0; i < 4; ++i) qv[i] = *(const float4*)&Qs[ty * 4 + i][k];
#pragma unroll
        for (int j = 0; j < 4; ++j) kv[j] = *(const float4*)&Ks[tx * 4 + j][k];
#pragma unroll
        for (int i = 0; i < 4; ++i)
#pragma unroll
          for (int j = 0; j < 4; ++j)
            S[i][j] += qv[i].x * kv[j].x + qv[i].y * kv[j].y
                     + qv[i].z * kv[j].z + qv[i].w * kv[j].w;
      }

      // ---- online softmax update (per query row, reduce across tx lanes) ----
#pragma unroll
      for (int i = 0; i < 4; ++i) {
        float mx = -1e30f;
#pragma unroll
        for (int j = 0; j < 4; ++j) {
          S[i][j] *= 0.125f;                             // 64^-0.5
          if (j0 + tx * 4 + j >= L_SEQ) S[i][j] = -1e30f;
          mx = fmaxf(mx, S[i][j]);
        }
#pragma unroll
        for (int o = 1; o < 16; o <<= 1) mx = fmaxf(mx, __shfl_xor(mx, o));
        const float mn = fmaxf(m[i], mx);
        const float corr = __expf(m[i] - mn);
        m[i] = mn;
        lsum[i] *= corr;
#pragma unroll
        for (int d = 0; d < 4; ++d) O[i][d] *= corr;
        float rs = 0.f;
#pragma unroll
        for (int j = 0; j < 4; ++j) {
          const float p = __expf(S[i][j] - mn);
          S[i][j] = p; rs += p;
        }
#pragma unroll
        for (int o = 1; o < 16; o <<= 1) rs += __shfl_xor(rs, o);
        lsum[i] += rs;
        *(float4*)&Ps[ty * 4 + i][tx * 4] = make_float4(S[i][0], S[i][1], S[i][2], S[i][3]);
      }

      if (att == 0) {                       // scores used K; PV needs V: re-stage
        __syncthreads();
        const int jl = j0 + lr;
        const int jr = jl < L_SEQ ? jl : (L_SEQ - 1);
        const float* src = qkv + (size_t)(jr * BATCH + b) * 2304 + 1536 + hoff;
#pragma unroll
        for (int q = 0; q < 4; ++q)
          *(float4*)&Ks[lr][lc4 + q * 16] = *(const float4*)(src + lc4 + q * 16);
      }
      __syncthreads();                      // Ps + V visible

      // ---- O[i][d] += sum_k P[qi][k] * V[k][d], d = tx*4..+3 ----
      for (int k = 0; k < 64; k += 4) {
        float4 pv[4], vv[4];
#pragma unroll
        for (int i = 0; i < 4; ++i) pv[i] = *(const float4*)&Ps[ty * 4 + i][k];
#pragma unroll
        for (int kk = 0; kk < 4; ++kk) vv[kk] = *(const float4*)&Ks[k + kk][tx * 4];
#pragma unroll
        for (int i = 0; i < 4; ++i) {
          O[i][0] += pv[i].x * vv[0].x + pv[i].y * vv[1].x + pv[i].z * vv[2].x + pv[i].w * vv[3].x;
          O[i][1] += pv[i].x * vv[0].y + pv[i].y * vv[1].y + pv[i].z * vv[2].y + pv[i].w * vv[3].y;
          O[i][2] += pv[i].x * vv[0].z + pv[i].y * vv[1].z + pv[i].z * vv[2].z + pv[i].w * vv[3].z;
          O[i][3] += pv[i].x * vv[0].w + pv[i].y * vv[1].w + pv[i].z * vv[2].w + pv[i].w * vv[3].w;
        }
      }
    }

    float* dst = att ? xo : xori;
#pragma unroll
    for (int i = 0; i < 4; ++i) {
      const int ql = q0 + ty * 4 + i;
      if (ql < L_SEQ) {
        const float rinv = 1.f / lsum[i];
        *(float4*)&dst[(size_t)(ql * BATCH + b) * CDIM + hoff + tx * 4] =
            make_float4(O[i][0] * rinv, O[i][1] * rinv, O[i][2] * rinv, O[i][3] * rinv);
      }
    }
  }
}

extern "C" void kernel_launch(void* const* d_in, const int* in_sizes, int n_in,
                              void* d_out, int out_size, void* d_ws, size_t ws_size,
                              hipStream_t stream)
{
  const float* x_res  = (const float*)d_in[0];
  const float* x      = (const float*)d_in[1];
  const float* ln1_g  = (const float*)d_in[2];
  const float* ln1_b  = (const float*)d_in[3];
  const float* ln2_g  = (const float*)d_in[4];
  const float* ln2_b  = (const float*)d_in[5];
  const float* qkv_w  = (const float*)d_in[6];
  const float* qkv_b  = (const float*)d_in[7];
  const float* proj_w = (const float*)d_in[8];
  const float* proj_b = (const float*)d_in[9];
  const float* fc_w   = (const float*)d_in[10];
  const float* fc_b   = (const float*)d_in[11];
  const float* cproj_w= (const float*)d_in[12];
  const float* cproj_b= (const float*)d_in[13];

  float* out_x  = (float*)d_out;          // x
  float* out_q  = out_x + LBC;            // q
  float* out_k  = out_x + 2 * LBC;        // k
  float* out_v  = out_x + 3 * LBC;        // v
  float* out_xr = out_x + 4 * LBC;        // x_res

  float* wsS    = (float*)d_ws;                       // max(ROWS*2304, ROWS*3072)
  float* wsLN   = wsS + (size_t)ROWS * 3072;
  float* wsXO   = wsLN + LBC;
  float* wsXORI = wsXO + LBC;

  const dim3 blk(256);
  const dim3 gLN((ROWS + 3) / 4);
  const dim3 gQKV(37, 18);
  const dim3 gPROJ(37, 6);
  const dim3 gFC(37, 24);
  const dim3 gATT((L_SEQ + 63) / 64, BATCH * NHEAD);

  ln_kernel<<<gLN, blk, 0, stream>>>(x, ln1_g, ln1_b, wsLN, ROWS);
  gemm_kernel<EPI_NONE><<<gQKV, blk, 0, stream>>>(wsLN, CDIM, qkv_w, CDIM, qkv_b,
                                                  wsS, 2304, nullptr, 0, ROWS);
  gemm_kernel<EPI_NONE><<<gPROJ, blk, 0, stream>>>(wsS + 0,    2304, proj_w, CDIM, proj_b,
                                                   out_q, CDIM, nullptr, 0, ROWS);
  gemm_kernel<EPI_NONE><<<gPROJ, blk, 0, stream>>>(wsS + 768,  2304, proj_w, CDIM, proj_b,
                                                   out_k, CDIM, nullptr, 0, ROWS);
  gemm_kernel<EPI_ADD><<<gPROJ, blk, 0, stream>>>(wsS + 1536, 2304, proj_w, CDIM, proj_b,
                                                  out_v, CDIM, x, CDIM, ROWS);
  attn_kernel<<<gATT, blk, 0, stream>>>(wsS, wsXO, wsXORI);
  gemm_kernel<EPI_ADD><<<gPROJ, blk, 0, stream>>>(wsXO, CDIM, proj_w, CDIM, proj_b,
                                                  out_xr, CDIM, x_res, CDIM, ROWS);
  gemm_kernel<EPI_ADD><<<gPROJ, blk, 0, stream>>>(wsXORI, CDIM, proj_w, CDIM, proj_b,
                                                  out_x, CDIM, x, CDIM, ROWS);
  ln_kernel<<<gLN, blk, 0, stream>>>(out_v, ln2_g, ln2_b, wsLN, ROWS);
  gemm_kernel<EPI_GELU><<<gFC, blk, 0, stream>>>(wsLN, CDIM, fc_w, CDIM, fc_b,
                                                 wsS, 3072, nullptr, 0, ROWS);
  gemm_kernel<EPI_ADD><<<gPROJ, blk, 0, stream>>>(wsS, 3072, cproj_w, 3072, cproj_b,
                                                  out_v, CDIM, out_v, CDIM, ROWS);
  ln_kernel<<<gLN, blk, 0, stream>>>(out_x, ln2_g, ln2_b, wsLN, ROWS);
  gemm_kernel<EPI_GELU><<<gFC, blk, 0, stream>>>(wsLN, CDIM, fc_w, CDIM, fc_b,
                                                 wsS, 3072, nullptr, 0, ROWS);
  gemm_kernel<EPI_ADD><<<gPROJ, blk, 0, stream>>>(wsS, 3072, cproj_w, 3072, cproj_b,
                                                  out_x, CDIM, out_x, CDIM, ROWS);
}

// Round 3
// 1158.065 us; speedup vs baseline: 4.5899x; 2.4828x over previous
//
#include <hip/hip_runtime.h>
#include <math.h>

#define L_SEQ 577
#define BATCH 8
#define CDIM  768
#define NHEAD 12
#define ROWS  (L_SEQ * BATCH)       // 4616
#define LBC   ((size_t)ROWS * CDIM) // 3545088

typedef __attribute__((ext_vector_type(8))) short bf16x8;
typedef __attribute__((ext_vector_type(4))) float f32x4;

enum { EPI_NONE = 0, EPI_ADD = 1, EPI_GELU = 2 };

__device__ __forceinline__ ushort f2bf(float f) {
  unsigned u = __float_as_uint(f);
  u += 0x7fffu + ((u >> 16) & 1u);
  return (ushort)(u >> 16);
}
__device__ __forceinline__ float bflo(unsigned u) { return __uint_as_float(u << 16); }
__device__ __forceinline__ float bfhi(unsigned u) { return __uint_as_float(u & 0xffff0000u); }

__device__ __forceinline__ void gload16(const void* g, void* l) {
  __builtin_amdgcn_global_load_lds(
      (const __attribute__((address_space(1))) unsigned int*)g,
      (__attribute__((address_space(3))) unsigned int*)l, 16, 0, 0);
}

__device__ __forceinline__ float wave_sum(float v) {
#pragma unroll
  for (int o = 32; o > 0; o >>= 1) v += __shfl_xor(v, o);
  return v;
}

// -------- fp32 -> bf16 cast (weights) --------
__global__ __launch_bounds__(256) void cast_bf16(const float* __restrict__ in,
                                                 ushort* __restrict__ out, int n4) {
  int i = blockIdx.x * blockDim.x + threadIdx.x;
  const int stride = gridDim.x * blockDim.x;
  for (; i < n4; i += stride) {
    float4 v = ((const float4*)in)[i];
    ushort4 o;
    o.x = f2bf(v.x); o.y = f2bf(v.y); o.z = f2bf(v.z); o.w = f2bf(v.w);
    ((ushort4*)out)[i] = o;
  }
}

// -------- LayerNorm: fp32 in, bf16 out; one wave per row of 768 --------
__global__ __launch_bounds__(256) void ln_kernel(
    const float* __restrict__ x, const float* __restrict__ g,
    const float* __restrict__ bta, ushort* __restrict__ out, int rows)
{
  const int wave = threadIdx.x >> 6, lane = threadIdx.x & 63;
  const int r = blockIdx.x * 4 + wave;
  if (r >= rows) return;
  const float4* xr = (const float4*)(x + (size_t)r * CDIM);
  float4 v[3];
  float s = 0.f, s2 = 0.f;
#pragma unroll
  for (int j = 0; j < 3; ++j) {
    v[j] = xr[lane + 64 * j];
    s  += v[j].x + v[j].y + v[j].z + v[j].w;
    s2 += v[j].x * v[j].x + v[j].y * v[j].y + v[j].z * v[j].z + v[j].w * v[j].w;
  }
  s = wave_sum(s); s2 = wave_sum(s2);
  const float mu = s * (1.f / 768.f);
  const float var = s2 * (1.f / 768.f) - mu * mu;
  const float rs = rsqrtf(var + 1e-5f);
  ushort4* orow = (ushort4*)(out + (size_t)r * CDIM);
#pragma unroll
  for (int j = 0; j < 3; ++j) {
    const int c4 = lane + 64 * j;
    const float4 gv = ((const float4*)g)[c4];
    const float4 bv = ((const float4*)bta)[c4];
    ushort4 o;
    o.x = f2bf((v[j].x - mu) * rs * gv.x + bv.x);
    o.y = f2bf((v[j].y - mu) * rs * gv.y + bv.y);
    o.z = f2bf((v[j].z - mu) * rs * gv.z + bv.z);
    o.w = f2bf((v[j].w - mu) * rs * gv.w + bv.w);
    orow[c4] = o;
  }
}

// -------- bf16 MFMA GEMM: C[M,N] = A[M,K] @ W[N,K]^T + bias (+epilogue) --------
// m97 2-barrier structure: global_load_lds(16B) staging -> ds_read_b128 frags
// -> mfma_f32_16x16x32_bf16. mfma(Wfrag, Afrag): lane&15 = m-row, regs = 4
// consecutive n-cols (verified C/D mapping: col=lane&15, row=(lane>>4)*4+reg).
template <int BM, int BN, int WM, int WN, int EPI, bool OBF>
__global__ __launch_bounds__(256) void mfma_gemm(
    const ushort* __restrict__ A, int lda,
    const ushort* __restrict__ W, int K,
    const float* __restrict__ bias,
    void* __restrict__ Cp, int ldc,
    const float* __restrict__ res, int ldr, int M)
{
  constexpr int BK = 32;
  __shared__ short As[BM * BK];
  __shared__ short Bs[BN * BK];
  const int t = threadIdx.x;
  const int wv = t >> 6, ln = t & 63;
  const int m0 = blockIdx.x * BM, n0 = blockIdx.y * BN;
  constexpr int NWM = BM / WM;
  const int wm = wv % NWM, wn = wv / NWM;
  constexpr int MF = WM / 16, NF = WN / 16;
  const int mbase = wm * WM, nbase = wn * WN;
  const int srow = ln >> 2;       // 16 rows per wave-instr
  const int schunk = ln & 3;      // which 16B chunk of the 64B row
  const int lrow15 = ln & 15;
  const int kchunk = (ln >> 4) * 8;

  f32x4 acc[MF][NF] = {};

  for (int k0 = 0; k0 < K; k0 += BK) {
    __syncthreads();
#pragma unroll
    for (int q = 0; q < BM / 64; ++q) {
      const int row = q * 64 + wv * 16 + srow;
      int grow = m0 + row; if (grow > M - 1) grow = M - 1;
      gload16(A + (size_t)grow * lda + k0 + schunk * 8,
              &As[(q * 64 + wv * 16) * BK]);
    }
#pragma unroll
    for (int q = 0; q < BN / 64; ++q) {
      const int row = q * 64 + wv * 16 + srow;
      gload16(W + (size_t)(n0 + row) * K + k0 + schunk * 8,
              &Bs[(q * 64 + wv * 16) * BK]);
    }
    __syncthreads();
    bf16x8 af[MF], wf[NF];
#pragma unroll
    for (int i = 0; i < MF; ++i)
      af[i] = *(const bf16x8*)&As[(mbase + i * 16 + lrow15) * BK + kchunk];
#pragma unroll
    for (int j = 0; j < NF; ++j)
      wf[j] = *(const bf16x8*)&Bs[(nbase + j * 16 + lrow15) * BK + kchunk];
#pragma unroll
    for (int i = 0; i < MF; ++i)
#pragma unroll
      for (int j = 0; j < NF; ++j)
        acc[i][j] = __builtin_amdgcn_mfma_f32_16x16x32_bf16(wf[j], af[i], acc[i][j], 0, 0, 0);
  }

  const int nq = (ln >> 4) * 4;
#pragma unroll
  for (int i = 0; i < MF; ++i) {
    const int m = m0 + mbase + i * 16 + lrow15;
    if (m >= M) continue;
#pragma unroll
    for (int j = 0; j < NF; ++j) {
      const int n = n0 + nbase + j * 16 + nq;
      const float4 bv = *(const float4*)&bias[n];
      float o0 = acc[i][j][0] + bv.x;
      float o1 = acc[i][j][1] + bv.y;
      float o2 = acc[i][j][2] + bv.z;
      float o3 = acc[i][j][3] + bv.w;
      if (EPI == EPI_GELU) {
        o0 = o0 / (1.f + __expf(-1.702f * o0));
        o1 = o1 / (1.f + __expf(-1.702f * o1));
        o2 = o2 / (1.f + __expf(-1.702f * o2));
        o3 = o3 / (1.f + __expf(-1.702f * o3));
      }
      if (EPI == EPI_ADD) {
        const float4 rv = *(const float4*)&res[(size_t)m * ldr + n];
        o0 += rv.x; o1 += rv.y; o2 += rv.z; o3 += rv.w;
      }
      if (OBF) {
        ushort4 ov;
        ov.x = f2bf(o0); ov.y = f2bf(o1); ov.z = f2bf(o2); ov.w = f2bf(o3);
        *(ushort4*)((ushort*)Cp + (size_t)m * ldc + n) = ov;
      } else {
        *(float4*)((float*)Cp + (size_t)m * ldc + n) = make_float4(o0, o1, o2, o3);
      }
    }
  }
}

// -------- v2v attention, flash-style LDS-tiled; bf16 in/out, fp32 math --------
__device__ __forceinline__ void cvt8(float* d, uint4 u) {
  d[0] = bflo(u.x); d[1] = bfhi(u.x);
  d[2] = bflo(u.y); d[3] = bfhi(u.y);
  d[4] = bflo(u.z); d[5] = bfhi(u.z);
  d[6] = bflo(u.w); d[7] = bfhi(u.w);
}

__global__ __launch_bounds__(256) void attn_kernel(
    const ushort* __restrict__ qkv,  // [ROWS, 2304] bf16, row r = l*BATCH + b
    ushort* __restrict__ xo,
    ushort* __restrict__ xori)
{
  __shared__ float Qs[64][65];
  __shared__ float Ks[64][65];
  __shared__ float Ps[64][65];
  const int t = threadIdx.x;
  const int tx = t & 15, ty = t >> 4;
  const int bh = blockIdx.y;
  const int b = bh / NHEAD, h = bh - b * NHEAD;
  const int q0 = blockIdx.x * 64;
  const int hoff = h * 64;
  const int lr = t >> 2;
  const int lc = (t & 3) * 16;

  for (int att = 0; att < 2; ++att) {
    const int xoff = att ? 1536 : 0;
    const int yoff = att ? 1536 : 768;
    __syncthreads();
    {
      const int ql = q0 + lr;
      const int qr = ql < L_SEQ ? ql : (L_SEQ - 1);
      const ushort* src = qkv + (size_t)(qr * BATCH + b) * 2304 + xoff + hoff + lc;
      cvt8(&Qs[lr][lc], *(const uint4*)src);
      cvt8(&Qs[lr][lc + 8], *(const uint4*)(src + 8));
    }

    float m[4], lsum[4], O[4][4];
#pragma unroll
    for (int i = 0; i < 4; ++i) {
      m[i] = -1e30f; lsum[i] = 0.f;
#pragma unroll
      for (int d = 0; d < 4; ++d) O[i][d] = 0.f;
    }

    for (int j0 = 0; j0 < L_SEQ; j0 += 64) {
      __syncthreads();
      {
        const int jl = j0 + lr;
        const int jr = jl < L_SEQ ? jl : (L_SEQ - 1);
        const ushort* src = qkv + (size_t)(jr * BATCH + b) * 2304 + yoff + hoff + lc;
        cvt8(&Ks[lr][lc], *(const uint4*)src);
        cvt8(&Ks[lr][lc + 8], *(const uint4*)(src + 8));
      }
      __syncthreads();

      float S[4][4] = {};
      for (int k = 0; k < 64; k += 4) {
        float4 qv[4], kv[4];
#pragma unroll
        for (int i = 0; i < 4; ++i) qv[i] = *(const float4*)&Qs[ty * 4 + i][k];
#pragma unroll
        for (int j = 0; j < 4; ++j) kv[j] = *(const float4*)&Ks[tx * 4 + j][k];
#pragma unroll
        for (int i = 0; i < 4; ++i)
#pragma unroll
          for (int j = 0; j < 4; ++j)
            S[i][j] += qv[i].x * kv[j].x + qv[i].y * kv[j].y
                     + qv[i].z * kv[j].z + qv[i].w * kv[j].w;
      }

#pragma unroll
      for (int i = 0; i < 4; ++i) {
        float mx = -1e30f;
#pragma unroll
        for (int j = 0; j < 4; ++j) {
          S[i][j] *= 0.125f;
          if (j0 + tx * 4 + j >= L_SEQ) S[i][j] = -1e30f;
          mx = fmaxf(mx, S[i][j]);
        }
#pragma unroll
        for (int o = 1; o < 16; o <<= 1) mx = fmaxf(mx, __shfl_xor(mx, o));
        const float mn = fmaxf(m[i], mx);
        const float corr = __expf(m[i] - mn);
        m[i] = mn;
        lsum[i] *= corr;
#pragma unroll
        for (int d = 0; d < 4; ++d) O[i][d] *= corr;
        float rsum = 0.f;
#pragma unroll
        for (int j = 0; j < 4; ++j) {
          const float p = __expf(S[i][j] - mn);
          S[i][j] = p; rsum += p;
        }
#pragma unroll
        for (int o = 1; o < 16; o <<= 1) rsum += __shfl_xor(rsum, o);
        lsum[i] += rsum;
        *(float4*)&Ps[ty * 4 + i][tx * 4] = make_float4(S[i][0], S[i][1], S[i][2], S[i][3]);
      }

      if (att == 0) {
        __syncthreads();
        const int jl = j0 + lr;
        const int jr = jl < L_SEQ ? jl : (L_SEQ - 1);
        const ushort* src = qkv + (size_t)(jr * BATCH + b) * 2304 + 1536 + hoff + lc;
        cvt8(&Ks[lr][lc], *(const uint4*)src);
        cvt8(&Ks[lr][lc + 8], *(const uint4*)(src + 8));
      }
      __syncthreads();

      for (int k = 0; k < 64; k += 4) {
        float4 pv[4], vv[4];
#pragma unroll
        for (int i = 0; i < 4; ++i) pv[i] = *(const float4*)&Ps[ty * 4 + i][k];
#pragma unroll
        for (int kk = 0; kk < 4; ++kk) vv[kk] = *(const float4*)&Ks[k + kk][tx * 4];
#pragma unroll
        for (int i = 0; i < 4; ++i) {
          O[i][0] += pv[i].x * vv[0].x + pv[i].y * vv[1].x + pv[i].z * vv[2].x + pv[i].w * vv[3].x;
          O[i][1] += pv[i].x * vv[0].y + pv[i].y * vv[1].y + pv[i].z * vv[2].y + pv[i].w * vv[3].y;
          O[i][2] += pv[i].x * vv[0].z + pv[i].y * vv[1].z + pv[i].z * vv[2].z + pv[i].w * vv[3].z;
          O[i][3] += pv[i].x * vv[0].w + pv[i].y * vv[1].w + pv[i].z * vv[2].w + pv[i].w * vv[3].w;
        }
      }
    }

    ushort* dst = att ? xo : xori;
#pragma unroll
    for (int i = 0; i < 4; ++i) {
      const int ql = q0 + ty * 4 + i;
      if (ql < L_SEQ) {
        const float rinv = 1.f / lsum[i];
        ushort4 o;
        o.x = f2bf(O[i][0] * rinv); o.y = f2bf(O[i][1] * rinv);
        o.z = f2bf(O[i][2] * rinv); o.w = f2bf(O[i][3] * rinv);
        *(ushort4*)&dst[(size_t)(ql * BATCH + b) * CDIM + hoff + tx * 4] = o;
      }
    }
  }
}

extern "C" void kernel_launch(void* const* d_in, const int* in_sizes, int n_in,
                              void* d_out, int out_size, void* d_ws, size_t ws_size,
                              hipStream_t stream)
{
  const float* x_res  = (const float*)d_in[0];
  const float* x      = (const float*)d_in[1];
  const float* ln1_g  = (const float*)d_in[2];
  const float* ln1_b  = (const float*)d_in[3];
  const float* ln2_g  = (const float*)d_in[4];
  const float* ln2_b  = (const float*)d_in[5];
  const float* qkv_w  = (const float*)d_in[6];
  const float* qkv_b  = (const float*)d_in[7];
  const float* proj_w = (const float*)d_in[8];
  const float* proj_b = (const float*)d_in[9];
  const float* fc_w   = (const float*)d_in[10];
  const float* fc_b   = (const float*)d_in[11];
  const float* cproj_w= (const float*)d_in[12];
  const float* cproj_b= (const float*)d_in[13];

  float* out_x  = (float*)d_out;
  float* out_q  = out_x + LBC;
  float* out_k  = out_x + 2 * LBC;
  float* out_v  = out_x + 3 * LBC;
  float* out_xr = out_x + 4 * LBC;

  // ws (all bf16/ushort): qkv-then-h shared region, ln, xo, xori, weights
  ushort* wsQKVH = (ushort*)d_ws;                     // ROWS*3072
  ushort* wsLN   = wsQKVH + (size_t)ROWS * 3072;
  ushort* wsXO   = wsLN + LBC;
  ushort* wsXORI = wsXO + LBC;
  ushort* wQKVW  = wsXORI + LBC;                      // 2304*768
  ushort* wPROJ  = wQKVW + (size_t)2304 * 768;        // 768*768
  ushort* wFC    = wPROJ + (size_t)768 * 768;         // 3072*768
  ushort* wCPROJ = wFC + (size_t)3072 * 768;          // 768*3072

  const dim3 blk(256);

  cast_bf16<<<1024, blk, 0, stream>>>(qkv_w,  wQKVW,  2304 * 768 / 4);
  cast_bf16<<<1024, blk, 0, stream>>>(proj_w, wPROJ,  768 * 768 / 4);
  cast_bf16<<<1024, blk, 0, stream>>>(fc_w,   wFC,    3072 * 768 / 4);
  cast_bf16<<<1024, blk, 0, stream>>>(cproj_w, wCPROJ, 768 * 3072 / 4);

  ln_kernel<<<dim3((ROWS + 3) / 4), blk, 0, stream>>>(x, ln1_g, ln1_b, wsLN, ROWS);

  mfma_gemm<128,128,64,64,EPI_NONE,true><<<dim3(37, 18), blk, 0, stream>>>(
      wsLN, CDIM, wQKVW, CDIM, qkv_b, wsQKVH, 2304, nullptr, 0, ROWS);

  mfma_gemm<64,128,32,64,EPI_NONE,false><<<dim3(73, 6), blk, 0, stream>>>(
      wsQKVH + 0,    2304, wPROJ, CDIM, proj_b, out_q, CDIM, nullptr, 0, ROWS);
  mfma_gemm<64,128,32,64,EPI_NONE,false><<<dim3(73, 6), blk, 0, stream>>>(
      wsQKVH + 768,  2304, wPROJ, CDIM, proj_b, out_k, CDIM, nullptr, 0, ROWS);
  mfma_gemm<64,128,32,64,EPI_ADD,false><<<dim3(73, 6), blk, 0, stream>>>(
      wsQKVH + 1536, 2304, wPROJ, CDIM, proj_b, out_v, CDIM, x, CDIM, ROWS);

  attn_kernel<<<dim3(10, 96), blk, 0, stream>>>(wsQKVH, wsXO, wsXORI);

  mfma_gemm<64,128,32,64,EPI_ADD,false><<<dim3(73, 6), blk, 0, stream>>>(
      wsXO,   CDIM, wPROJ, CDIM, proj_b, out_xr, CDIM, x_res, CDIM, ROWS);
  mfma_gemm<64,128,32,64,EPI_ADD,false><<<dim3(73, 6), blk, 0, stream>>>(
      wsXORI, CDIM, wPROJ, CDIM, proj_b, out_x, CDIM, x, CDIM, ROWS);

  ln_kernel<<<dim3((ROWS + 3) / 4), blk, 0, stream>>>(out_v, ln2_g, ln2_b, wsLN, ROWS);
  mfma_gemm<128,128,64,64,EPI_GELU,true><<<dim3(37, 24), blk, 0, stream>>>(
      wsLN, CDIM, wFC, CDIM, fc_b, wsQKVH, 3072, nullptr, 0, ROWS);
  mfma_gemm<64,128,32,64,EPI_ADD,false><<<dim3(73, 6), blk, 0, stream>>>(
      wsQKVH, 3072, wCPROJ, 3072, cproj_b, out_v, CDIM, out_v, CDIM, ROWS);

  ln_kernel<<<dim3((ROWS + 3) / 4), blk, 0, stream>>>(out_x, ln2_g, ln2_b, wsLN, ROWS);
  mfma_gemm<128,128,64,64,EPI_GELU,true><<<dim3(37, 24), blk, 0, stream>>>(
      wsLN, CDIM, wFC, CDIM, fc_b, wsQKVH, 3072, nullptr, 0, ROWS);
  mfma_gemm<64,128,32,64,EPI_ADD,false><<<dim3(73, 6), blk, 0, stream>>>(
      wsQKVH, 3072, wCPROJ, 3072, cproj_b, out_x, CDIM, out_x, CDIM, ROWS);
}

// Round 4
// 560.058 us; speedup vs baseline: 9.4907x; 2.0678x over previous
//
#include <hip/hip_runtime.h>
#include <math.h>

#define L_SEQ 577
#define BATCH 8
#define CDIM  768
#define NHEAD 12
#define ROWS  (L_SEQ * BATCH)       // 4616
#define LBC   ((size_t)ROWS * CDIM) // 3545088

typedef __attribute__((ext_vector_type(8))) short bf16x8;
typedef __attribute__((ext_vector_type(4))) float f32x4;

enum { EPI_NONE = 0, EPI_ADD = 1, EPI_GELU = 2 };

__device__ __forceinline__ ushort f2bf(float f) {
  unsigned u = __float_as_uint(f);
  u += 0x7fffu + ((u >> 16) & 1u);
  return (ushort)(u >> 16);
}

__device__ __forceinline__ void gload16(const void* g, void* l) {
  __builtin_amdgcn_global_load_lds(
      (const __attribute__((address_space(1))) unsigned int*)g,
      (__attribute__((address_space(3))) unsigned int*)l, 16, 0, 0);
}

__device__ __forceinline__ float wave_sum(float v) {
#pragma unroll
  for (int o = 32; o > 0; o >>= 1) v += __shfl_xor(v, o);
  return v;
}

// -------- fp32 -> bf16 cast (weights) --------
__global__ __launch_bounds__(256) void cast_bf16(const float* __restrict__ in,
                                                 ushort* __restrict__ out, int n4) {
  int i = blockIdx.x * blockDim.x + threadIdx.x;
  const int stride = gridDim.x * blockDim.x;
  for (; i < n4; i += stride) {
    float4 v = ((const float4*)in)[i];
    ushort4 o;
    o.x = f2bf(v.x); o.y = f2bf(v.y); o.z = f2bf(v.z); o.w = f2bf(v.w);
    ((ushort4*)out)[i] = o;
  }
}

// -------- LayerNorm: fp32 in, bf16 out; one wave per row of 768 --------
__global__ __launch_bounds__(256) void ln_kernel(
    const float* __restrict__ x, const float* __restrict__ g,
    const float* __restrict__ bta, ushort* __restrict__ out, int rows)
{
  const int wave = threadIdx.x >> 6, lane = threadIdx.x & 63;
  const int r = blockIdx.x * 4 + wave;
  if (r >= rows) return;
  const float4* xr = (const float4*)(x + (size_t)r * CDIM);
  float4 v[3];
  float s = 0.f, s2 = 0.f;
#pragma unroll
  for (int j = 0; j < 3; ++j) {
    v[j] = xr[lane + 64 * j];
    s  += v[j].x + v[j].y + v[j].z + v[j].w;
    s2 += v[j].x * v[j].x + v[j].y * v[j].y + v[j].z * v[j].z + v[j].w * v[j].w;
  }
  s = wave_sum(s); s2 = wave_sum(s2);
  const float mu = s * (1.f / 768.f);
  const float var = s2 * (1.f / 768.f) - mu * mu;
  const float rs = rsqrtf(var + 1e-5f);
  ushort4* orow = (ushort4*)(out + (size_t)r * CDIM);
#pragma unroll
  for (int j = 0; j < 3; ++j) {
    const int c4 = lane + 64 * j;
    const float4 gv = ((const float4*)g)[c4];
    const float4 bv = ((const float4*)bta)[c4];
    ushort4 o;
    o.x = f2bf((v[j].x - mu) * rs * gv.x + bv.x);
    o.y = f2bf((v[j].y - mu) * rs * gv.y + bv.y);
    o.z = f2bf((v[j].z - mu) * rs * gv.z + bv.z);
    o.w = f2bf((v[j].w - mu) * rs * gv.w + bv.w);
    orow[c4] = o;
  }
}

// -------- bf16 MFMA GEMM (m97 2-barrier structure), unchanged --------
template <int BM, int BN, int WM, int WN, int EPI, bool OBF>
__global__ __launch_bounds__(256) void mfma_gemm(
    const ushort* __restrict__ A, int lda,
    const ushort* __restrict__ W, int K,
    const float* __restrict__ bias,
    void* __restrict__ Cp, int ldc,
    const float* __restrict__ res, int ldr, int M)
{
  constexpr int BK = 32;
  __shared__ short As[BM * BK];
  __shared__ short Bs[BN * BK];
  const int t = threadIdx.x;
  const int wv = t >> 6, ln = t & 63;
  const int m0 = blockIdx.x * BM, n0 = blockIdx.y * BN;
  constexpr int NWM = BM / WM;
  const int wm = wv % NWM, wn = wv / NWM;
  constexpr int MF = WM / 16, NF = WN / 16;
  const int mbase = wm * WM, nbase = wn * WN;
  const int srow = ln >> 2;
  const int schunk = ln & 3;
  const int lrow15 = ln & 15;
  const int kchunk = (ln >> 4) * 8;

  f32x4 acc[MF][NF] = {};

  for (int k0 = 0; k0 < K; k0 += BK) {
    __syncthreads();
#pragma unroll
    for (int q = 0; q < BM / 64; ++q) {
      const int row = q * 64 + wv * 16 + srow;
      int grow = m0 + row; if (grow > M - 1) grow = M - 1;
      gload16(A + (size_t)grow * lda + k0 + schunk * 8,
              &As[(q * 64 + wv * 16) * BK]);
    }
#pragma unroll
    for (int q = 0; q < BN / 64; ++q) {
      const int row = q * 64 + wv * 16 + srow;
      gload16(W + (size_t)(n0 + row) * K + k0 + schunk * 8,
              &Bs[(q * 64 + wv * 16) * BK]);
    }
    __syncthreads();
    bf16x8 af[MF], wf[NF];
#pragma unroll
    for (int i = 0; i < MF; ++i)
      af[i] = *(const bf16x8*)&As[(mbase + i * 16 + lrow15) * BK + kchunk];
#pragma unroll
    for (int j = 0; j < NF; ++j)
      wf[j] = *(const bf16x8*)&Bs[(nbase + j * 16 + lrow15) * BK + kchunk];
#pragma unroll
    for (int i = 0; i < MF; ++i)
#pragma unroll
      for (int j = 0; j < NF; ++j)
        acc[i][j] = __builtin_amdgcn_mfma_f32_16x16x32_bf16(wf[j], af[i], acc[i][j], 0, 0, 0);
  }

  const int nq = (ln >> 4) * 4;
#pragma unroll
  for (int i = 0; i < MF; ++i) {
    const int m = m0 + mbase + i * 16 + lrow15;
    if (m >= M) continue;
#pragma unroll
    for (int j = 0; j < NF; ++j) {
      const int n = n0 + nbase + j * 16 + nq;
      const float4 bv = *(const float4*)&bias[n];
      float o0 = acc[i][j][0] + bv.x;
      float o1 = acc[i][j][1] + bv.y;
      float o2 = acc[i][j][2] + bv.z;
      float o3 = acc[i][j][3] + bv.w;
      if (EPI == EPI_GELU) {
        o0 = o0 / (1.f + __expf(-1.702f * o0));
        o1 = o1 / (1.f + __expf(-1.702f * o1));
        o2 = o2 / (1.f + __expf(-1.702f * o2));
        o3 = o3 / (1.f + __expf(-1.702f * o3));
      }
      if (EPI == EPI_ADD) {
        const float4 rv = *(const float4*)&res[(size_t)m * ldr + n];
        o0 += rv.x; o1 += rv.y; o2 += rv.z; o3 += rv.w;
      }
      if (OBF) {
        ushort4 ov;
        ov.x = f2bf(o0); ov.y = f2bf(o1); ov.z = f2bf(o2); ov.w = f2bf(o3);
        *(ushort4*)((ushort*)Cp + (size_t)m * ldc + n) = ov;
      } else {
        *(float4*)((float*)Cp + (size_t)m * ldc + n) = make_float4(o0, o1, o2, o3);
      }
    }
  }
}

// -------- v2v attention, MFMA flash-style --------
// Block = (b,h) x 64 q-rows; 4 waves x 16 q-rows each. Both softmaxes
// (q.k -> xori, v.v -> xo) share one j-loop and one V/Vt staging.
// Layout reuses the HW-validated GEMM mapping:
//   A-op: lane holds M[l&15][(l>>4)*8+0..7]; B-op: col = l&15;
//   D: col = l&15, row = (l>>4)*4 + reg.
__global__ __launch_bounds__(256) void attn_kernel(
    const ushort* __restrict__ qkv,  // [ROWS,2304] bf16, row r = l*BATCH+b
    ushort* __restrict__ xo,
    ushort* __restrict__ xori)
{
  __shared__ short Ks[64 * 72];      // K rows, stride 72 (pad kills 128B-row conflicts)
  __shared__ short Vs[64 * 72];      // V rows (keys for v.v pass)
  __shared__ short Vt[64 * 72];      // V transposed [d][j], j XOR-swizzled by 8*(d>>3)
  __shared__ short Ps[4][16 * 72];   // per-wave P repack scratch
  const int t = threadIdx.x;
  const int w = t >> 6, l = t & 63;
  const int b = blockIdx.y / NHEAD, h = blockIdx.y - (blockIdx.y / NHEAD) * NHEAD;
  const int q0 = blockIdx.x * 64;
  const int hoff = h * 64;
  const int l15 = l & 15, l16 = l >> 4;

  // Query fragments (B-op): att0 = Q rows, att1 = V rows. Held in regs.
  const int qrow0 = q0 + w * 16 + l15;
  const int qrow = qrow0 < L_SEQ ? qrow0 : (L_SEQ - 1);
  const size_t qbase = (size_t)(qrow * BATCH + b) * 2304 + hoff;
  bf16x8 qf[2][2];
#pragma unroll
  for (int ks = 0; ks < 2; ++ks) {
    qf[0][ks] = *(const bf16x8*)(qkv + qbase + 0    + ks * 32 + l16 * 8);
    qf[1][ks] = *(const bf16x8*)(qkv + qbase + 1536 + ks * 32 + l16 * 8);
  }

  float mS[2] = {-1e30f, -1e30f};
  float lS[2] = {0.f, 0.f};
  f32x4 accO[2][4] = {};

  const int sr = t >> 3;          // stage row base 0..31
  const int sc = (t & 7) * 8;     // stage col base (also the Vt swizzle: 8*(d>>3))

  for (int j0 = 0; j0 < 640; j0 += 64) {
    __syncthreads();
#pragma unroll
    for (int rep = 0; rep < 2; ++rep) {
      const int r = rep * 32 + sr;
      const int jl = j0 + r;
      const int jr = jl < L_SEQ ? jl : (L_SEQ - 1);
      const size_t gb = (size_t)(jr * BATCH + b) * 2304 + hoff + sc;
      const uint4 kv = *(const uint4*)(qkv + gb + 768);
      const uint4 vv = *(const uint4*)(qkv + gb + 1536);
      *(uint4*)&Ks[r * 72 + sc] = kv;
      *(uint4*)&Vs[r * 72 + sc] = vv;
      const ushort* vp = (const ushort*)&vv;
#pragma unroll
      for (int e = 0; e < 8; ++e)
        Vt[(sc + e) * 72 + (r ^ sc)] = vp[e];   // swz = 8*(d>>3) = sc here
    }
    __syncthreads();

#pragma unroll
    for (int att = 0; att < 2; ++att) {
      const short* keys = att ? Vs : Ks;
      // S = keys x query^T : D col = q (l&15), row = j within frag
      f32x4 S[4] = {};
#pragma unroll
      for (int ks = 0; ks < 2; ++ks)
#pragma unroll
        for (int f = 0; f < 4; ++f) {
          const bf16x8 kf = *(const bf16x8*)&keys[(f * 16 + l15) * 72 + ks * 32 + l16 * 8];
          S[f] = __builtin_amdgcn_mfma_f32_16x16x32_bf16(kf, qf[att][ks], S[f], 0, 0, 0);
        }

      float tmax = -1e30f;
#pragma unroll
      for (int f = 0; f < 4; ++f)
#pragma unroll
        for (int r = 0; r < 4; ++r) {
          float s = S[f][r] * 0.125f;
          if (j0 + f * 16 + l16 * 4 + r >= L_SEQ) s = -1e30f;
          S[f][r] = s;
          tmax = fmaxf(tmax, s);
        }
      tmax = fmaxf(tmax, __shfl_xor(tmax, 16));
      tmax = fmaxf(tmax, __shfl_xor(tmax, 32));
      const float mold = mS[att];
      const float mnew = fmaxf(mold, tmax);
      const float corr = __expf(mold - mnew);
      mS[att] = mnew;

      float tsum = 0.f;
#pragma unroll
      for (int f = 0; f < 4; ++f) {
        ushort pb[4];
#pragma unroll
        for (int r = 0; r < 4; ++r) {
          const float p = __expf(S[f][r] - mnew);
          tsum += p;
          pb[r] = f2bf(p);
        }
        uint2 pk;
        pk.x = (unsigned)pb[0] | ((unsigned)pb[1] << 16);
        pk.y = (unsigned)pb[2] | ((unsigned)pb[3] << 16);
        *(uint2*)&Ps[w][l15 * 72 + f * 16 + l16 * 4] = pk;
      }
      tsum += __shfl_xor(tsum, 16);
      tsum += __shfl_xor(tsum, 32);
      lS[att] = lS[att] * corr + tsum;

      // move corr (indexed by q=l&15) to O layout (q = l16*4+reg)
      float corr4[4];
#pragma unroll
      for (int r = 0; r < 4; ++r) corr4[r] = __shfl(corr, l16 * 4 + r);
#pragma unroll
      for (int df = 0; df < 4; ++df)
#pragma unroll
        for (int r = 0; r < 4; ++r) accO[att][df][r] *= corr4[r];

      // O += P x V : A-op = P (rows q), B-op = Vt (col d)
#pragma unroll
      for (int ks = 0; ks < 2; ++ks) {
        const bf16x8 pf = *(const bf16x8*)&Ps[w][l15 * 72 + ks * 32 + l16 * 8];
#pragma unroll
        for (int df = 0; df < 4; ++df) {
          const int d = df * 16 + l15;
          const int s8 = (d >> 3) * 8;
          const bf16x8 vf = *(const bf16x8*)&Vt[d * 72 + ((ks * 32 + l16 * 8) ^ s8)];
          accO[att][df] = __builtin_amdgcn_mfma_f32_16x16x32_bf16(pf, vf, accO[att][df], 0, 0, 0);
        }
      }
    }
  }

#pragma unroll
  for (int att = 0; att < 2; ++att) {
    const float linv = 1.f / lS[att];
    float r4[4];
#pragma unroll
    for (int r = 0; r < 4; ++r) r4[r] = __shfl(linv, l16 * 4 + r);
    ushort* dst = att ? xo : xori;
#pragma unroll
    for (int r = 0; r < 4; ++r) {
      const int qq = q0 + w * 16 + l16 * 4 + r;
      if (qq < L_SEQ) {
        ushort* orow = dst + (size_t)(qq * BATCH + b) * CDIM + hoff + l15;
#pragma unroll
        for (int df = 0; df < 4; ++df)
          orow[df * 16] = f2bf(accO[att][df][r] * r4[r]);
      }
    }
  }
}

extern "C" void kernel_launch(void* const* d_in, const int* in_sizes, int n_in,
                              void* d_out, int out_size, void* d_ws, size_t ws_size,
                              hipStream_t stream)
{
  const float* x_res  = (const float*)d_in[0];
  const float* x      = (const float*)d_in[1];
  const float* ln1_g  = (const float*)d_in[2];
  const float* ln1_b  = (const float*)d_in[3];
  const float* ln2_g  = (const float*)d_in[4];
  const float* ln2_b  = (const float*)d_in[5];
  const float* qkv_w  = (const float*)d_in[6];
  const float* qkv_b  = (const float*)d_in[7];
  const float* proj_w = (const float*)d_in[8];
  const float* proj_b = (const float*)d_in[9];
  const float* fc_w   = (const float*)d_in[10];
  const float* fc_b   = (const float*)d_in[11];
  const float* cproj_w= (const float*)d_in[12];
  const float* cproj_b= (const float*)d_in[13];

  float* out_x  = (float*)d_out;
  float* out_q  = out_x + LBC;
  float* out_k  = out_x + 2 * LBC;
  float* out_v  = out_x + 3 * LBC;
  float* out_xr = out_x + 4 * LBC;

  ushort* wsQKVH = (ushort*)d_ws;                     // ROWS*3072
  ushort* wsLN   = wsQKVH + (size_t)ROWS * 3072;
  ushort* wsXO   = wsLN + LBC;
  ushort* wsXORI = wsXO + LBC;
  ushort* wQKVW  = wsXORI + LBC;
  ushort* wPROJ  = wQKVW + (size_t)2304 * 768;
  ushort* wFC    = wPROJ + (size_t)768 * 768;
  ushort* wCPROJ = wFC + (size_t)3072 * 768;

  const dim3 blk(256);

  cast_bf16<<<1024, blk, 0, stream>>>(qkv_w,  wQKVW,  2304 * 768 / 4);
  cast_bf16<<<1024, blk, 0, stream>>>(proj_w, wPROJ,  768 * 768 / 4);
  cast_bf16<<<1024, blk, 0, stream>>>(fc_w,   wFC,    3072 * 768 / 4);
  cast_bf16<<<1024, blk, 0, stream>>>(cproj_w, wCPROJ, 768 * 3072 / 4);

  ln_kernel<<<dim3((ROWS + 3) / 4), blk, 0, stream>>>(x, ln1_g, ln1_b, wsLN, ROWS);

  mfma_gemm<128,128,64,64,EPI_NONE,true><<<dim3(37, 18), blk, 0, stream>>>(
      wsLN, CDIM, wQKVW, CDIM, qkv_b, wsQKVH, 2304, nullptr, 0, ROWS);

  mfma_gemm<64,128,32,64,EPI_NONE,false><<<dim3(73, 6), blk, 0, stream>>>(
      wsQKVH + 0,    2304, wPROJ, CDIM, proj_b, out_q, CDIM, nullptr, 0, ROWS);
  mfma_gemm<64,128,32,64,EPI_NONE,false><<<dim3(73, 6), blk, 0, stream>>>(
      wsQKVH + 768,  2304, wPROJ, CDIM, proj_b, out_k, CDIM, nullptr, 0, ROWS);
  mfma_gemm<64,128,32,64,EPI_ADD,false><<<dim3(73, 6), blk, 0, stream>>>(
      wsQKVH + 1536, 2304, wPROJ, CDIM, proj_b, out_v, CDIM, x, CDIM, ROWS);

  attn_kernel<<<dim3(10, 96), blk, 0, stream>>>(wsQKVH, wsXO, wsXORI);

  mfma_gemm<64,128,32,64,EPI_ADD,false><<<dim3(73, 6), blk, 0, stream>>>(
      wsXO,   CDIM, wPROJ, CDIM, proj_b, out_xr, CDIM, x_res, CDIM, ROWS);
  mfma_gemm<64,128,32,64,EPI_ADD,false><<<dim3(73, 6), blk, 0, stream>>>(
      wsXORI, CDIM, wPROJ, CDIM, proj_b, out_x, CDIM, x, CDIM, ROWS);

  ln_kernel<<<dim3((ROWS + 3) / 4), blk, 0, stream>>>(out_v, ln2_g, ln2_b, wsLN, ROWS);
  mfma_gemm<128,128,64,64,EPI_GELU,true><<<dim3(37, 24), blk, 0, stream>>>(
      wsLN, CDIM, wFC, CDIM, fc_b, wsQKVH, 3072, nullptr, 0, ROWS);
  mfma_gemm<64,128,32,64,EPI_ADD,false><<<dim3(73, 6), blk, 0, stream>>>(
      wsQKVH, 3072, wCPROJ, 3072, cproj_b, out_v, CDIM, out_v, CDIM, ROWS);

  ln_kernel<<<dim3((ROWS + 3) / 4), blk, 0, stream>>>(out_x, ln2_g, ln2_b, wsLN, ROWS);
  mfma_gemm<128,128,64,64,EPI_GELU,true><<<dim3(37, 24), blk, 0, stream>>>(
      wsLN, CDIM, wFC, CDIM, fc_b, wsQKVH, 3072, nullptr, 0, ROWS);
  mfma_gemm<64,128,32,64,EPI_ADD,false><<<dim3(73, 6), blk, 0, stream>>>(
      wsQKVH, 3072, wCPROJ, 3072, cproj_b, out_x, CDIM, out_x, CDIM, ROWS);
}

// Round 7
// 498.308 us; speedup vs baseline: 10.6668x; 1.1239x over previous
//
#include <hip/hip_runtime.h>
#include <math.h>

#define L_SEQ 577
#define BATCH 8
#define CDIM  768
#define NHEAD 12
#define ROWS  (L_SEQ * BATCH)       // 4616
#define LBC   ((size_t)ROWS * CDIM) // 3545088

typedef __attribute__((ext_vector_type(8))) short bf16x8;
typedef __attribute__((ext_vector_type(4))) float f32x4;

__device__ __forceinline__ ushort f2bf(float f) {
  unsigned u = __float_as_uint(f);
  u += 0x7fffu + ((u >> 16) & 1u);
  return (ushort)(u >> 16);
}

__device__ __forceinline__ void gload16(const void* g, void* l) {
  __builtin_amdgcn_global_load_lds(
      (const __attribute__((address_space(1))) unsigned int*)g,
      (__attribute__((address_space(3))) unsigned int*)l, 16, 0, 0);
}

__device__ __forceinline__ float wave_sum(float v) {
#pragma unroll
  for (int o = 32; o > 0; o >>= 1) v += __shfl_xor(v, o);
  return v;
}

// -------- fp32 -> bf16 cast (weights) --------
__global__ __launch_bounds__(256) void cast_bf16(const float* __restrict__ in,
                                                 ushort* __restrict__ out, int n4) {
  int i = blockIdx.x * blockDim.x + threadIdx.x;
  const int stride = gridDim.x * blockDim.x;
  for (; i < n4; i += stride) {
    float4 v = ((const float4*)in)[i];
    ushort4 o;
    o.x = f2bf(v.x); o.y = f2bf(v.y); o.z = f2bf(v.z); o.w = f2bf(v.w);
    ((ushort4*)out)[i] = o;
  }
}

// -------- LayerNorm (optionally 2 sources): fp32 in, bf16 out --------
__global__ __launch_bounds__(256) void ln_kernel(
    const float* __restrict__ srcA, const float* __restrict__ srcB,
    const float* __restrict__ g, const float* __restrict__ bta,
    ushort* __restrict__ out, int rowsTotal, int rowsPer)
{
  const int wave = threadIdx.x >> 6, lane = threadIdx.x & 63;
  const int r = blockIdx.x * 4 + wave;
  if (r >= rowsTotal) return;
  const float4* xr = (r < rowsPer)
      ? (const float4*)(srcA + (size_t)r * CDIM)
      : (const float4*)(srcB + (size_t)(r - rowsPer) * CDIM);
  float4 v[3];
  float s = 0.f, s2 = 0.f;
#pragma unroll
  for (int j = 0; j < 3; ++j) {
    v[j] = xr[lane + 64 * j];
    s  += v[j].x + v[j].y + v[j].z + v[j].w;
    s2 += v[j].x * v[j].x + v[j].y * v[j].y + v[j].z * v[j].z + v[j].w * v[j].w;
  }
  s = wave_sum(s); s2 = wave_sum(s2);
  const float mu = s * (1.f / 768.f);
  const float var = s2 * (1.f / 768.f) - mu * mu;
  const float rs = rsqrtf(var + 1e-5f);
  ushort4* orow = (ushort4*)(out + (size_t)r * CDIM);
#pragma unroll
  for (int j = 0; j < 3; ++j) {
    const int c4 = lane + 64 * j;
    const float4 gv = ((const float4*)g)[c4];
    const float4 bv = ((const float4*)bta)[c4];
    ushort4 o;
    o.x = f2bf((v[j].x - mu) * rs * gv.x + bv.x);
    o.y = f2bf((v[j].y - mu) * rs * gv.y + bv.y);
    o.z = f2bf((v[j].z - mu) * rs * gv.z + bv.z);
    o.w = f2bf((v[j].w - mu) * rs * gv.w + bv.w);
    orow[c4] = o;
  }
}

// -------- bf16 MFMA GEMM, z-sliced + XCD-swizzled --------
// K-loop identical to the round-3 kernel (m97 2-barrier structure).
// z-slice: A += z*a_zoff; C/res picked per z. 128x128 tile, 4 waves x 64x64.
template <bool GELU, bool OBF>
__global__ __launch_bounds__(256) void mfma_gemm(
    const ushort* __restrict__ A, int lda, size_t a_zoff,
    const ushort* __restrict__ W, int K,
    const float* __restrict__ bias,
    void* __restrict__ C0, void* __restrict__ C1, void* __restrict__ C2, int ldc,
    const float* __restrict__ R0, const float* __restrict__ R1,
    const float* __restrict__ R2, int ldr, int M)
{
  constexpr int BM = 128, BN = 128, BK = 32;
  __shared__ short As[BM * BK];
  __shared__ short Bs[BN * BK];
  const int t = threadIdx.x;
  const int wv = t >> 6, ln = t & 63;

  // bijective XCD-aware swizzle (m204) within this z-slice
  const int nwg = gridDim.x * gridDim.y;
  const int orig = blockIdx.x + gridDim.x * blockIdx.y;
  const int qq = nwg >> 3, rr = nwg & 7;
  const int xcd = orig & 7, lid = orig >> 3;
  const int wg = (xcd < rr ? xcd * (qq + 1) : rr * (qq + 1) + (xcd - rr) * qq) + lid;
  const int m0 = (wg % gridDim.x) * BM, n0 = (wg / gridDim.x) * BN;

  const int z = blockIdx.z;
  const ushort* Az = A + (size_t)z * a_zoff;
  void* Cv = z == 0 ? C0 : (z == 1 ? C1 : C2);
  const float* res = z == 0 ? R0 : (z == 1 ? R1 : R2);

  const int wm = wv & 1, wn = wv >> 1;       // 2x2 waves of 64x64
  const int mbase = wm * 64, nbase = wn * 64;
  const int srow = ln >> 2;
  const int schunk = ln & 3;
  const int lrow15 = ln & 15;
  const int kchunk = (ln >> 4) * 8;

  f32x4 acc[4][4] = {};

  for (int k0 = 0; k0 < K; k0 += BK) {
    __syncthreads();
#pragma unroll
    for (int q = 0; q < 2; ++q) {
      const int row = q * 64 + wv * 16 + srow;
      int grow = m0 + row; if (grow > M - 1) grow = M - 1;
      gload16(Az + (size_t)grow * lda + k0 + schunk * 8,
              &As[(q * 64 + wv * 16) * BK]);
    }
#pragma unroll
    for (int q = 0; q < 2; ++q) {
      const int row = q * 64 + wv * 16 + srow;
      gload16(W + (size_t)(n0 + row) * K + k0 + schunk * 8,
              &Bs[(q * 64 + wv * 16) * BK]);
    }
    __syncthreads();
    bf16x8 af[4], wf[4];
#pragma unroll
    for (int i = 0; i < 4; ++i)
      af[i] = *(const bf16x8*)&As[(mbase + i * 16 + lrow15) * BK + kchunk];
#pragma unroll
    for (int j = 0; j < 4; ++j)
      wf[j] = *(const bf16x8*)&Bs[(nbase + j * 16 + lrow15) * BK + kchunk];
#pragma unroll
    for (int i = 0; i < 4; ++i)
#pragma unroll
      for (int j = 0; j < 4; ++j)
        acc[i][j] = __builtin_amdgcn_mfma_f32_16x16x32_bf16(wf[j], af[i], acc[i][j], 0, 0, 0);
  }

  const int nq = (ln >> 4) * 4;
#pragma unroll
  for (int i = 0; i < 4; ++i) {
    const int m = m0 + mbase + i * 16 + lrow15;
    if (m >= M) continue;
#pragma unroll
    for (int j = 0; j < 4; ++j) {
      const int n = n0 + nbase + j * 16 + nq;
      const float4 bv = *(const float4*)&bias[n];
      float o0 = acc[i][j][0] + bv.x;
      float o1 = acc[i][j][1] + bv.y;
      float o2 = acc[i][j][2] + bv.z;
      float o3 = acc[i][j][3] + bv.w;
      if (GELU) {
        o0 = o0 / (1.f + __expf(-1.702f * o0));
        o1 = o1 / (1.f + __expf(-1.702f * o1));
        o2 = o2 / (1.f + __expf(-1.702f * o2));
        o3 = o3 / (1.f + __expf(-1.702f * o3));
      }
      if (res) {
        const float4 rv = *(const float4*)&res[(size_t)m * ldr + n];
        o0 += rv.x; o1 += rv.y; o2 += rv.z; o3 += rv.w;
      }
      if (OBF) {
        ushort4 ov;
        ov.x = f2bf(o0); ov.y = f2bf(o1); ov.z = f2bf(o2); ov.w = f2bf(o3);
        *(ushort4*)((ushort*)Cv + (size_t)m * ldc + n) = ov;
      } else {
        *(float4*)((float*)Cv + (size_t)m * ldc + n) = make_float4(o0, o1, o2, o3);
      }
    }
  }
}

// -------- v2v attention, MFMA flash-style (unchanged from round 4) --------
__global__ __launch_bounds__(256) void attn_kernel(
    const ushort* __restrict__ qkv,  // [ROWS,2304] bf16, row r = l*BATCH+b
    ushort* __restrict__ xo,
    ushort* __restrict__ xori)
{
  __shared__ short Ks[64 * 72];
  __shared__ short Vs[64 * 72];
  __shared__ short Vt[64 * 72];
  __shared__ short Ps[4][16 * 72];
  const int t = threadIdx.x;
  const int w = t >> 6, l = t & 63;
  const int b = blockIdx.y / NHEAD, h = blockIdx.y - (blockIdx.y / NHEAD) * NHEAD;
  const int q0 = blockIdx.x * 64;
  const int hoff = h * 64;
  const int l15 = l & 15, l16 = l >> 4;

  const int qrow0 = q0 + w * 16 + l15;
  const int qrow = qrow0 < L_SEQ ? qrow0 : (L_SEQ - 1);
  const size_t qbase = (size_t)(qrow * BATCH + b) * 2304 + hoff;
  bf16x8 qf[2][2];
#pragma unroll
  for (int ks = 0; ks < 2; ++ks) {
    qf[0][ks] = *(const bf16x8*)(qkv + qbase + 0    + ks * 32 + l16 * 8);
    qf[1][ks] = *(const bf16x8*)(qkv + qbase + 1536 + ks * 32 + l16 * 8);
  }

  float mS[2] = {-1e30f, -1e30f};
  float lS[2] = {0.f, 0.f};
  f32x4 accO[2][4] = {};

  const int sr = t >> 3;
  const int sc = (t & 7) * 8;

  for (int j0 = 0; j0 < 640; j0 += 64) {
    __syncthreads();
#pragma unroll
    for (int rep = 0; rep < 2; ++rep) {
      const int r = rep * 32 + sr;
      const int jl = j0 + r;
      const int jr = jl < L_SEQ ? jl : (L_SEQ - 1);
      const size_t gb = (size_t)(jr * BATCH + b) * 2304 + hoff + sc;
      const uint4 kv = *(const uint4*)(qkv + gb + 768);
      const uint4 vv = *(const uint4*)(qkv + gb + 1536);
      *(uint4*)&Ks[r * 72 + sc] = kv;
      *(uint4*)&Vs[r * 72 + sc] = vv;
      const ushort* vp = (const ushort*)&vv;
#pragma unroll
      for (int e = 0; e < 8; ++e)
        Vt[(sc + e) * 72 + (r ^ sc)] = vp[e];
    }
    __syncthreads();

#pragma unroll
    for (int att = 0; att < 2; ++att) {
      const short* keys = att ? Vs : Ks;
      f32x4 S[4] = {};
#pragma unroll
      for (int ks = 0; ks < 2; ++ks)
#pragma unroll
        for (int f = 0; f < 4; ++f) {
          const bf16x8 kf = *(const bf16x8*)&keys[(f * 16 + l15) * 72 + ks * 32 + l16 * 8];
          S[f] = __builtin_amdgcn_mfma_f32_16x16x32_bf16(kf, qf[att][ks], S[f], 0, 0, 0);
        }

      float tmax = -1e30f;
#pragma unroll
      for (int f = 0; f < 4; ++f)
#pragma unroll
        for (int r = 0; r < 4; ++r) {
          float s = S[f][r] * 0.125f;
          if (j0 + f * 16 + l16 * 4 + r >= L_SEQ) s = -1e30f;
          S[f][r] = s;
          tmax = fmaxf(tmax, s);
        }
      tmax = fmaxf(tmax, __shfl_xor(tmax, 16));
      tmax = fmaxf(tmax, __shfl_xor(tmax, 32));
      const float mold = mS[att];
      const float mnew = fmaxf(mold, tmax);
      const float corr = __expf(mold - mnew);
      mS[att] = mnew;

      float tsum = 0.f;
#pragma unroll
      for (int f = 0; f < 4; ++f) {
        ushort pb[4];
#pragma unroll
        for (int r = 0; r < 4; ++r) {
          const float p = __expf(S[f][r] - mnew);
          tsum += p;
          pb[r] = f2bf(p);
        }
        uint2 pk;
        pk.x = (unsigned)pb[0] | ((unsigned)pb[1] << 16);
        pk.y = (unsigned)pb[2] | ((unsigned)pb[3] << 16);
        *(uint2*)&Ps[w][l15 * 72 + f * 16 + l16 * 4] = pk;
      }
      tsum += __shfl_xor(tsum, 16);
      tsum += __shfl_xor(tsum, 32);
      lS[att] = lS[att] * corr + tsum;

      float corr4[4];
#pragma unroll
      for (int r = 0; r < 4; ++r) corr4[r] = __shfl(corr, l16 * 4 + r);
#pragma unroll
      for (int df = 0; df < 4; ++df)
#pragma unroll
        for (int r = 0; r < 4; ++r) accO[att][df][r] *= corr4[r];

#pragma unroll
      for (int ks = 0; ks < 2; ++ks) {
        const bf16x8 pf = *(const bf16x8*)&Ps[w][l15 * 72 + ks * 32 + l16 * 8];
#pragma unroll
        for (int df = 0; df < 4; ++df) {
          const int d = df * 16 + l15;
          const int s8 = (d >> 3) * 8;
          const bf16x8 vf = *(const bf16x8*)&Vt[d * 72 + ((ks * 32 + l16 * 8) ^ s8)];
          accO[att][df] = __builtin_amdgcn_mfma_f32_16x16x32_bf16(pf, vf, accO[att][df], 0, 0, 0);
        }
      }
    }
  }

#pragma unroll
  for (int att = 0; att < 2; ++att) {
    const float linv = 1.f / lS[att];
    float r4[4];
#pragma unroll
    for (int r = 0; r < 4; ++r) r4[r] = __shfl(linv, l16 * 4 + r);
    ushort* dst = att ? xo : xori;
#pragma unroll
    for (int r = 0; r < 4; ++r) {
      const int qq = q0 + w * 16 + l16 * 4 + r;
      if (qq < L_SEQ) {
        ushort* orow = dst + (size_t)(qq * BATCH + b) * CDIM + hoff + l15;
#pragma unroll
        for (int df = 0; df < 4; ++df)
          orow[df * 16] = f2bf(accO[att][df][r] * r4[r]);
      }
    }
  }
}

extern "C" void kernel_launch(void* const* d_in, const int* in_sizes, int n_in,
                              void* d_out, int out_size, void* d_ws, size_t ws_size,
                              hipStream_t stream)
{
  const float* x_res  = (const float*)d_in[0];
  const float* x      = (const float*)d_in[1];
  const float* ln1_g  = (const float*)d_in[2];
  const float* ln1_b  = (const float*)d_in[3];
  const float* ln2_g  = (const float*)d_in[4];
  const float* ln2_b  = (const float*)d_in[5];
  const float* qkv_w  = (const float*)d_in[6];
  const float* qkv_b  = (const float*)d_in[7];
  const float* proj_w = (const float*)d_in[8];
  const float* proj_b = (const float*)d_in[9];
  const float* fc_w   = (const float*)d_in[10];
  const float* fc_b   = (const float*)d_in[11];
  const float* cproj_w= (const float*)d_in[12];
  const float* cproj_b= (const float*)d_in[13];

  float* out_x  = (float*)d_out;
  float* out_q  = out_x + LBC;
  float* out_k  = out_x + 2 * LBC;
  float* out_v  = out_x + 3 * LBC;
  float* out_xr = out_x + 4 * LBC;

  // ws layout (bf16): [wsH: 2*ROWS*3072, holds qkv then fc-out; XO/XORI in tail]
  //                   [wsLN: 2*LBC] [weights]
  ushort* wsH    = (ushort*)d_ws;
  ushort* wsXO   = wsH + (size_t)ROWS * 2304;
  ushort* wsXORI = wsXO + LBC;
  ushort* wsLN   = wsH + (size_t)2 * ROWS * 3072;
  ushort* wQKVW  = wsLN + 2 * LBC;
  ushort* wPROJ  = wQKVW + (size_t)2304 * 768;
  ushort* wFC    = wPROJ + (size_t)768 * 768;
  ushort* wCPROJ = wFC + (size_t)3072 * 768;

  const dim3 blk(256);

  cast_bf16<<<1024, blk, 0, stream>>>(qkv_w,  wQKVW,  2304 * 768 / 4);
  cast_bf16<<<1024, blk, 0, stream>>>(proj_w, wPROJ,  768 * 768 / 4);
  cast_bf16<<<1024, blk, 0, stream>>>(fc_w,   wFC,    3072 * 768 / 4);
  cast_bf16<<<1024, blk, 0, stream>>>(cproj_w, wCPROJ, 768 * 3072 / 4);

  // LN1(x) -> wsLN
  ln_kernel<<<dim3((ROWS + 3) / 4), blk, 0, stream>>>(
      x, x, ln1_g, ln1_b, wsLN, ROWS, ROWS);

  // qkv = LN1 @ qkv_w^T + b  -> wsH [ROWS,2304] bf16
  mfma_gemm<false, true><<<dim3(37, 18, 1), blk, 0, stream>>>(
      wsLN, CDIM, 0, wQKVW, CDIM, qkv_b,
      wsH, nullptr, nullptr, 2304,
      nullptr, nullptr, nullptr, 0, ROWS);

  // q/k/v projections, z-batched (z=2 adds x residual into out_v)
  mfma_gemm<false, false><<<dim3(37, 6, 3), blk, 0, stream>>>(
      wsH, 2304, 768, wPROJ, CDIM, proj_b,
      out_q, out_k, out_v, CDIM,
      nullptr, nullptr, x, CDIM, ROWS);

  attn_kernel<<<dim3(10, 96), blk, 0, stream>>>(wsH, wsXO, wsXORI);

  // attention-output projections, z-batched: out_xr = x_res + proj(xo); x1 = x + proj(xori)
  mfma_gemm<false, false><<<dim3(37, 6, 2), blk, 0, stream>>>(
      wsXO, CDIM, LBC, wPROJ, CDIM, proj_b,
      out_xr, out_x, nullptr, CDIM,
      x_res, x, nullptr, CDIM, ROWS);

  // LN2 over [v1 ; x1] -> wsLN [2*ROWS, 768]
  ln_kernel<<<dim3((2 * ROWS + 3) / 4), blk, 0, stream>>>(
      out_v, out_x, ln2_g, ln2_b, wsLN, 2 * ROWS, ROWS);

  // fc + quickGELU, batched M=2*ROWS -> wsH [2*ROWS,3072] bf16
  mfma_gemm<true, true><<<dim3(73, 24, 1), blk, 0, stream>>>(
      wsLN, CDIM, 0, wFC, CDIM, fc_b,
      wsH, nullptr, nullptr, 3072,
      nullptr, nullptr, nullptr, 0, 2 * ROWS);

  // cproj, z-batched: out_v += cproj(h_v); out_x += cproj(h_x)
  mfma_gemm<false, false><<<dim3(37, 6, 2), blk, 0, stream>>>(
      wsH, 3072, (size_t)ROWS * 3072, wCPROJ, 3072, cproj_b,
      out_v, out_x, nullptr, CDIM,
      out_v, out_x, nullptr, CDIM, ROWS);
}